// Round 9
// baseline (4242.919 us; speedup 1.0000x reference)
//
#include <hip/hip_runtime.h>
#include <hip/hip_bf16.h>

#define T_SEQ 512
#define BATCH 256
#define HID   1024
#define EMBD  256
#define NCLS  10

typedef __bf16 bf16x8 __attribute__((ext_vector_type(8)));
typedef float  floatx16 __attribute__((ext_vector_type(16)));
typedef float  floatx4 __attribute__((ext_vector_type(4)));
typedef unsigned short ushortx8 __attribute__((ext_vector_type(8)));

__device__ __forceinline__ unsigned int f2bf(float f) {
    unsigned int u = __builtin_bit_cast(unsigned int, f);
    u += 0x7fffu + ((u >> 16) & 1u);
    return u >> 16;
}
__device__ __forceinline__ float sig_fast(float x) {
    return __builtin_amdgcn_rcpf(1.0f + __expf(-x));
}
__device__ __forceinline__ float tanh_fast(float x) {
    return 1.0f - 2.0f * __builtin_amdgcn_rcpf(1.0f + __expf(2.0f * x));
}

// -------------------- prep: XW[tok][gate][n] = emb[tok] @ Wx_gate + b_gate ---
__global__ void prep_xw_kernel(const float* __restrict__ emb,
                               const float* __restrict__ wgx, const float* __restrict__ wix,
                               const float* __restrict__ wfx, const float* __restrict__ wox,
                               const float* __restrict__ bg,  const float* __restrict__ bi,
                               const float* __restrict__ bf,  const float* __restrict__ bo,
                               float* __restrict__ XW) {
    int gid = blockIdx.x * blockDim.x + threadIdx.x;     // 3*4*1024 = 12288
    if (gid >= 3 * 4 * HID) return;
    int tok  = gid >> 12;
    int gate = (gid >> 10) & 3;
    int n    = gid & 1023;
    const float* W = gate == 0 ? wgx : gate == 1 ? wix : gate == 2 ? wfx : wox;
    const float* B = gate == 0 ? bg  : gate == 1 ? bi  : gate == 2 ? bf  : bo;
    float acc = B[n];
    const float* e = emb + tok * EMBD;
    for (int k = 0; k < EMBD; ++k) acc += e[k] * W[k * HID + n];
    XW[gid] = acc;
}

// ---- prep: Wt in 32x32x16 MFMA B-fragment order, K-quarter granularity ----
// frag = ((w*4+g)*4+q)*16 + i ; Wt[frag*512 + lane*8 + e]
//   = bf16( W_g[k = q*256 + i*16 + (lane>>5)*8 + e][j = w*32 + (lane&31)] )
__global__ void prep_w_kernel(const float* __restrict__ wgh, const float* __restrict__ wih,
                              const float* __restrict__ wfh, const float* __restrict__ woh,
                              unsigned short* __restrict__ Wt) {
    int bid = blockIdx.x;                 // 8192 = g(2b) q(2b) i(4b) w(5b)
    int w   = bid & 31;
    int i   = (bid >> 5) & 15;
    int q   = (bid >> 9) & 3;
    int g   = bid >> 11;
    const float* W = g == 0 ? wgh : g == 1 ? wih : g == 2 ? wfh : woh;
    int lane = threadIdx.x;               // 64
    int j    = w * 32 + (lane & 31);
    int k0   = q * 256 + i * 16 + (lane >> 5) * 8;
    ushortx8 o8;
    #pragma unroll
    for (int e = 0; e < 8; ++e) o8[e] = (unsigned short)f2bf(W[(k0 + e) * HID + j]);
    int frag = ((w * 4 + g) * 4 + q) * 16 + i;
    *(ushortx8*)&Wt[frag * 512 + lane * 8] = o8;
}

// -------------------- persistent recurrent kernel ---------------------------
// 256 WGs x 256 threads (4 waves, 1/SIMD). grp = blockIdx%8 owns 32 batch
// rows; w = blockIdx/8 owns 32 hidden cols. Wave q = K-quarter, ALL 4 gates
// (B: 4x16 frags = 256 regs/lane). hs quarter is wave-private: staged and
// read only by wave q => zero stage barriers. gbuf transposed [col][row] so
// both C-scatter (regs 0..3 = 4 consecutive rows) and elementwise reads are
// ds_*_b128. Publish = per-wave counter increment after vmcnt drain; spin on
// global counters only (no LDS-port pollution - R8 lesson). Exchange scopes =
// R7-proven (same-XCD write-back local path; system fallback).
__global__ __launch_bounds__(256, 1)
void lstm_kernel(const int* __restrict__ x, const float* __restrict__ XW,
                 const unsigned short* __restrict__ Wt,
                 unsigned int* __restrict__ hbuf32, int* __restrict__ flags,
                 int* __restrict__ xflag) {
    __shared__ __align__(16) unsigned short hs[4][32][264];   // 67584 B
    __shared__ __align__(16) float gbufT[16][32][36];         // [g*4+q][col][row+pad] 73728 B
    __shared__ unsigned char xtokp[4096];                     // [step][rowblock] packed
    __shared__ int use_local_sh;

    const int tid  = threadIdx.x;
    const int grp  = blockIdx.x & 7;
    const int w    = blockIdx.x >> 3;
    const int q    = tid >> 6;                 // K-quarter = wave id
    const int lane = tid & 63;
    const int m32  = lane & 31;
    const int hv5  = lane >> 5;

    // ---- XCD-locality check (one-time, system-scope => placement-safe) ----
    {
        int xcc = 0;
        asm volatile("s_getreg_b32 %0, hwreg(HW_REG_XCC_ID)" : "=s"(xcc));
        if (tid == 0) {
            __hip_atomic_store(&xflag[grp * 32 + w], xcc + 1, __ATOMIC_RELAXED,
                               __HIP_MEMORY_SCOPE_SYSTEM);
        }
        if (q == 0) {
            int v;
            for (;;) {
                v = __hip_atomic_load(&xflag[grp * 32 + (lane & 31)], __ATOMIC_RELAXED,
                                      __HIP_MEMORY_SCOPE_SYSTEM);
                if (__all(v != 0)) break;
                __builtin_amdgcn_s_sleep(2);
            }
            int v0 = __shfl(v, 0, 64);
            if (lane == 0) use_local_sh = __all(v == v0) ? 1 : 0;
        }
    }

    // one-time: B fragments, 4 gates x 16 frags (256 regs/lane)
    bf16x8 Bf[4][16];
    #pragma unroll
    for (int g = 0; g < 4; ++g) {
        const unsigned short* wb = Wt + (size_t)(((w * 4 + g) * 4 + q) * 16) * 512
                                      + (size_t)lane * 8;
        #pragma unroll
        for (int i = 0; i < 16; ++i)
            Bf[g][i] = *(const bf16x8*)(wb + i * 512);
    }

    // elementwise ownership: col c = tid&31, rows rb..rb+3 (rb = (tid>>5)*4)
    const int c  = tid & 31;
    const int rb = (tid >> 5) * 4;

    // one-time: XW for this thread's column, all toks/gates -> 12 registers
    float xw0[4], xw1[4], xw2[4];
    #pragma unroll
    for (int g = 0; g < 4; ++g) {
        xw0[g] = XW[(0 * 4 + g) * HID + w * 32 + c];
        xw1[g] = XW[(1 * 4 + g) * HID + w * 32 + c];
        xw2[g] = XW[(2 * 4 + g) * HID + w * 32 + c];
    }

    // one-time: token table, byte = 4 rowblock tokens at one step
    for (int i = tid; i < 4096; i += 256) {
        int s_ = i >> 3, blk = i & 7;
        int t0 = x[(grp * 32 + blk * 4 + 0) * T_SEQ + s_] & 3;
        int t1 = x[(grp * 32 + blk * 4 + 1) * T_SEQ + s_] & 3;
        int t2 = x[(grp * 32 + blk * 4 + 2) * T_SEQ + s_] & 3;
        int t3 = x[(grp * 32 + blk * 4 + 3) * T_SEQ + s_] & 3;
        xtokp[i] = (unsigned char)(t0 | (t1 << 2) | (t2 << 4) | (t3 << 6));
    }
    __syncthreads();
    const bool use_local = (use_local_sh != 0);

    float cst[4] = {0.f, 0.f, 0.f, 0.f};
    unsigned long long* hsq = (unsigned long long*)&hs[q][0][0];  // row stride 66 qw

    for (int s = 0; s < T_SEQ; ++s) {
        // ---- spin: this quarter's 8 producers, counter >= 4*s ----
        if (s > 0) {
            const int fidx = grp * 32 + q * 8 + (lane & 7);
            const int target = 4 * s;
            if (use_local) {
                for (;;) {
                    int v = __hip_atomic_load(&flags[fidx], __ATOMIC_RELAXED,
                                              __HIP_MEMORY_SCOPE_AGENT);
                    if (__all(v >= target)) break;
                    __builtin_amdgcn_s_sleep(1);
                }
            } else {
                for (;;) {
                    int v = __hip_atomic_load(&flags[fidx], __ATOMIC_RELAXED,
                                              __HIP_MEMORY_SCOPE_SYSTEM);
                    if (__all(v >= target)) break;
                    __builtin_amdgcn_s_sleep(1);
                }
            }
        }

        // ---- stage own quarter (wave-private, no barrier): 16 KB ----
        {
            const unsigned long long* hp64 = (const unsigned long long*)
                (hbuf32 + (size_t)(s & 1) * (BATCH * HID / 2));
            #pragma unroll
            for (int half = 0; half < 2; ++half) {
                unsigned long long tmp[16];
                #pragma unroll
                for (int it = 0; it < 16; ++it) {
                    int chunk = (half * 16 + it) * 64 + lane;   // 0..2047
                    int r  = chunk >> 6;
                    int kq = chunk & 63;
                    const unsigned long long* src =
                        &hp64[(size_t)(grp * 32 + r) * 256 + q * 64 + kq];
                    tmp[it] = use_local
                        ? __hip_atomic_load(src, __ATOMIC_RELAXED, __HIP_MEMORY_SCOPE_AGENT)
                        : __hip_atomic_load(src, __ATOMIC_RELAXED, __HIP_MEMORY_SCOPE_SYSTEM);
                }
                #pragma unroll
                for (int it = 0; it < 16; ++it) {
                    int chunk = (half * 16 + it) * 64 + lane;
                    int r  = chunk >> 6;
                    int kq = chunk & 63;
                    hsq[r * 66 + kq] = tmp[it];
                }
            }
        }
        asm volatile("s_waitcnt lgkmcnt(0)" ::: "memory");   // own writes -> own reads

        // ---- GEMM: 4 gates x 32x32 over this wave's K-quarter ----
        floatx16 acc[4];
        #pragma unroll
        for (int g = 0; g < 4; ++g) acc[g] = (floatx16)(0.f);
        const unsigned short* ap = &hs[q][m32][hv5 * 8];
        #pragma unroll
        for (int i = 0; i < 16; ++i) {
            bf16x8 a = *(const bf16x8*)(ap + i * 16);
            acc[0] = __builtin_amdgcn_mfma_f32_32x32x16_bf16(a, Bf[0][i], acc[0], 0, 0, 0);
            acc[1] = __builtin_amdgcn_mfma_f32_32x32x16_bf16(a, Bf[1][i], acc[1], 0, 0, 0);
            acc[2] = __builtin_amdgcn_mfma_f32_32x32x16_bf16(a, Bf[2][i], acc[2], 0, 0, 0);
            acc[3] = __builtin_amdgcn_mfma_f32_32x32x16_bf16(a, Bf[3][i], acc[3], 0, 0, 0);
        }

        // ---- scatter transposed: regs 4rr..4rr+3 = rows 8rr+4hv5.. (b128) ----
        #pragma unroll
        for (int g = 0; g < 4; ++g) {
            #pragma unroll
            for (int rr = 0; rr < 4; ++rr) {
                floatx4 v = { acc[g][4 * rr + 0], acc[g][4 * rr + 1],
                              acc[g][4 * rr + 2], acc[g][4 * rr + 3] };
                *(floatx4*)&gbufT[g * 4 + q][m32][8 * rr + 4 * hv5] = v;
            }
        }
        __syncthreads();   // B1: all 16 partial tiles ready

        // ---- elementwise: col c, rows rb..rb+3 ----
        {
            int byte = xtokp[s * 8 + (tid >> 5)];
            floatx4 ag = *(const floatx4*)&gbufT[0][c][rb] + *(const floatx4*)&gbufT[1][c][rb]
                       + *(const floatx4*)&gbufT[2][c][rb] + *(const floatx4*)&gbufT[3][c][rb];
            floatx4 ai = *(const floatx4*)&gbufT[4][c][rb] + *(const floatx4*)&gbufT[5][c][rb]
                       + *(const floatx4*)&gbufT[6][c][rb] + *(const floatx4*)&gbufT[7][c][rb];
            floatx4 af = *(const floatx4*)&gbufT[8][c][rb] + *(const floatx4*)&gbufT[9][c][rb]
                       + *(const floatx4*)&gbufT[10][c][rb] + *(const floatx4*)&gbufT[11][c][rb];
            floatx4 ao = *(const floatx4*)&gbufT[12][c][rb] + *(const floatx4*)&gbufT[13][c][rb]
                       + *(const floatx4*)&gbufT[14][c][rb] + *(const floatx4*)&gbufT[15][c][rb];
            unsigned short* hnext = (unsigned short*)
                (hbuf32 + (size_t)((s + 1) & 1) * (BATCH * HID / 2));
            #pragma unroll
            for (int i = 0; i < 4; ++i) {
                int tk = (byte >> (2 * i)) & 3;
                float xg = tk == 0 ? xw0[0] : (tk == 1 ? xw1[0] : xw2[0]);
                float xi = tk == 0 ? xw0[1] : (tk == 1 ? xw1[1] : xw2[1]);
                float xf = tk == 0 ? xw0[2] : (tk == 1 ? xw1[2] : xw2[2]);
                float xo = tk == 0 ? xw0[3] : (tk == 1 ? xw1[3] : xw2[3]);
                float g  = tanh_fast(ag[i] + xg);
                float ii = sig_fast(ai[i] + xi);
                float ff = sig_fast(af[i] + xf);
                float oo = sig_fast(ao[i] + xo);
                float cn = g * ii + cst[i] * ff;
                float h  = tanh_fast(cn) * oo;
                cst[i]   = (tk != 0) ? cn : 0.0f;   // pad = ((x+1)//2) in {0,1,1}
                unsigned short hv = (unsigned short)f2bf(h);
                unsigned short* hp = &hnext[(size_t)(grp * 32 + rb + i) * HID + w * 32 + c];
                if (use_local) {
                    __hip_atomic_store(hp, hv, __ATOMIC_RELAXED, __HIP_MEMORY_SCOPE_WORKGROUP);
                } else {
                    __hip_atomic_store(hp, hv, __ATOMIC_RELAXED, __HIP_MEMORY_SCOPE_SYSTEM);
                }
            }
        }

        // ---- per-wave publish: stores drained to L2, then counter +1 ----
        if (s < T_SEQ - 1) {
            asm volatile("s_waitcnt vmcnt(0)" ::: "memory");
            if (lane == 0) {
                if (use_local) {
                    __hip_atomic_fetch_add(&flags[grp * 32 + w], 1, __ATOMIC_RELAXED,
                                           __HIP_MEMORY_SCOPE_AGENT);
                } else {
                    __hip_atomic_fetch_add(&flags[grp * 32 + w], 1, __ATOMIC_RELEASE,
                                           __HIP_MEMORY_SCOPE_SYSTEM);
                }
            }
        }
        __syncthreads();   // B2: gbuf reads done before next scatter
    }
}

// -------------------- projection + log_softmax over batch dim ---------------
__global__ void proj_kernel(const unsigned short* __restrict__ h,
                            const float* __restrict__ wph, const float* __restrict__ bp,
                            float* __restrict__ out) {
    __shared__ float wl[HID * NCLS];
    __shared__ float red[256];
    int tid = threadIdx.x;      // = batch row
    for (int i = tid; i < HID * NCLS; i += 256) wl[i] = wph[i];
    __syncthreads();
    float p[NCLS];
    #pragma unroll
    for (int c2 = 0; c2 < NCLS; ++c2) p[c2] = bp[c2];
    const unsigned short* hr = h + tid * HID;
    for (int k0 = 0; k0 < HID / 8; ++k0) {
        bf16x8 hv = *(const bf16x8*)(hr + k0 * 8);
        #pragma unroll
        for (int j = 0; j < 8; ++j) {
            float hk = (float)hv[j];
            #pragma unroll
            for (int c2 = 0; c2 < NCLS; ++c2) p[c2] += hk * wl[(k0 * 8 + j) * NCLS + c2];
        }
    }
    for (int c2 = 0; c2 < NCLS; ++c2) {
        red[tid] = p[c2];
        __syncthreads();
        for (int s = 128; s > 0; s >>= 1) {
            if (tid < s) red[tid] = fmaxf(red[tid], red[tid + s]);
            __syncthreads();
        }
        float mx = red[0];
        __syncthreads();
        red[tid] = __expf(p[c2] - mx);
        __syncthreads();
        for (int s = 128; s > 0; s >>= 1) {
            if (tid < s) red[tid] += red[tid + s];
            __syncthreads();
        }
        float lse = mx + __logf(red[0]);
        __syncthreads();
        out[tid * NCLS + c2] = p[c2] - lse;
    }
}

// ----------------------------------------------------------------------------
extern "C" void kernel_launch(void* const* d_in, const int* in_sizes, int n_in,
                              void* d_out, int out_size, void* d_ws, size_t ws_size,
                              hipStream_t stream) {
    const int*   x    = (const int*)d_in[0];
    const float* emb  = (const float*)d_in[1];
    const float* wgx  = (const float*)d_in[2];
    const float* wgh  = (const float*)d_in[3];
    const float* bg_  = (const float*)d_in[4];
    const float* wix  = (const float*)d_in[5];
    const float* wih  = (const float*)d_in[6];
    const float* bi_  = (const float*)d_in[7];
    const float* wfx  = (const float*)d_in[8];
    const float* wfh  = (const float*)d_in[9];
    const float* bf_  = (const float*)d_in[10];
    const float* wox  = (const float*)d_in[11];
    const float* woh  = (const float*)d_in[12];
    const float* bo_  = (const float*)d_in[13];
    const float* wph  = (const float*)d_in[14];
    const float* bp_  = (const float*)d_in[15];
    float* out = (float*)d_out;

    char* wsp = (char*)d_ws;
    int*            flags = (int*)wsp;                                      // 4 KB
    int*            xflag = (int*)(wsp + 4096);                             // 4 KB
    float*          XW    = (float*)(wsp + 8192);                           // 48 KB
    unsigned short* Wt    = (unsigned short*)(wsp + 8192 + 49152);          // 8 MB
    unsigned int*   hbuf32= (unsigned int*)(wsp + 8192 + 49152 + 8388608);  // 1 MB

    hipMemsetAsync(flags, 0, 8192, stream);                                  // flags+xflag
    hipMemsetAsync(hbuf32, 0, BATCH * HID * sizeof(unsigned short), stream); // h0 = 0

    prep_xw_kernel<<<48, 256, 0, stream>>>(emb, wgx, wix, wfx, wox,
                                           bg_, bi_, bf_, bo_, XW);
    prep_w_kernel<<<8192, 64, 0, stream>>>(wgh, wih, wfh, woh, Wt);

    void* args[] = { (void*)&x, (void*)&XW, (void*)&Wt, (void*)&hbuf32,
                     (void*)&flags, (void*)&xflag };
    hipError_t cerr = hipLaunchCooperativeKernel((void*)lstm_kernel, dim3(256), dim3(256),
                                                 args, 0, stream);
    if (cerr != hipSuccess) {
        // Fallback: plain launch. The counter protocol needs only co-residency,
        // which grid=256 at 1 WG/CU provides.
        lstm_kernel<<<dim3(256), dim3(256), 0, stream>>>(x, XW, Wt, hbuf32, flags, xflag);
    }

    proj_kernel<<<1, 256, 0, stream>>>((const unsigned short*)hbuf32, wph, bp_, out);
}

// Round 10
// 2008.104 us; speedup vs baseline: 2.1129x; 2.1129x over previous
//
#include <hip/hip_runtime.h>
#include <hip/hip_bf16.h>

#define T_SEQ 512
#define BATCH 256
#define HID   1024
#define EMBD  256
#define NCLS  10

typedef __bf16 bf16x8 __attribute__((ext_vector_type(8)));
typedef float  floatx16 __attribute__((ext_vector_type(16)));
typedef float  floatx4 __attribute__((ext_vector_type(4)));
typedef float  floatx2 __attribute__((ext_vector_type(2)));
typedef unsigned short ushortx8 __attribute__((ext_vector_type(8)));

__device__ __forceinline__ unsigned int f2bf(float f) {
    unsigned int u = __builtin_bit_cast(unsigned int, f);
    u += 0x7fffu + ((u >> 16) & 1u);
    return u >> 16;
}
__device__ __forceinline__ float sig_fast(float x) {
    return __builtin_amdgcn_rcpf(1.0f + __expf(-x));
}
__device__ __forceinline__ float tanh_fast(float x) {
    return 1.0f - 2.0f * __builtin_amdgcn_rcpf(1.0f + __expf(2.0f * x));
}

// -------------------- prep: XW[tok][gate][n] = emb[tok] @ Wx_gate + b_gate ---
__global__ void prep_xw_kernel(const float* __restrict__ emb,
                               const float* __restrict__ wgx, const float* __restrict__ wix,
                               const float* __restrict__ wfx, const float* __restrict__ wox,
                               const float* __restrict__ bg,  const float* __restrict__ bi,
                               const float* __restrict__ bf,  const float* __restrict__ bo,
                               float* __restrict__ XW) {
    int gid = blockIdx.x * blockDim.x + threadIdx.x;     // 3*4*1024 = 12288
    if (gid >= 3 * 4 * HID) return;
    int tok  = gid >> 12;
    int gate = (gid >> 10) & 3;
    int n    = gid & 1023;
    const float* W = gate == 0 ? wgx : gate == 1 ? wix : gate == 2 ? wfx : wox;
    const float* B = gate == 0 ? bg  : gate == 1 ? bi  : gate == 2 ? bf  : bo;
    float acc = B[n];
    const float* e = emb + tok * EMBD;
    for (int k = 0; k < EMBD; ++k) acc += e[k] * W[k * HID + n];
    XW[gid] = acc;
}

// ---- prep: Wt in 32x32x16 MFMA B-fragment order, K-quarter granularity ----
// frag = ((w*4+g)*4+q)*16 + i ; Wt[frag*512 + lane*8 + e]
//   = bf16( W_g[k = q*256 + i*16 + (lane>>5)*8 + e][j = w*32 + (lane&31)] )
__global__ void prep_w_kernel(const float* __restrict__ wgh, const float* __restrict__ wih,
                              const float* __restrict__ wfh, const float* __restrict__ woh,
                              unsigned short* __restrict__ Wt) {
    int bid = blockIdx.x;                 // 8192 = g(2b) q(2b) i(4b) w(5b)
    int w   = bid & 31;
    int i   = (bid >> 5) & 15;
    int q   = (bid >> 9) & 3;
    int g   = bid >> 11;
    const float* W = g == 0 ? wgh : g == 1 ? wih : g == 2 ? wfh : woh;
    int lane = threadIdx.x;               // 64
    int j    = w * 32 + (lane & 31);
    int k0   = q * 256 + i * 16 + (lane >> 5) * 8;
    ushortx8 o8;
    #pragma unroll
    for (int e = 0; e < 8; ++e) o8[e] = (unsigned short)f2bf(W[(k0 + e) * HID + j]);
    int frag = ((w * 4 + g) * 4 + q) * 16 + i;
    *(ushortx8*)&Wt[frag * 512 + lane * 8] = o8;
}

// -------------------- persistent recurrent kernel ---------------------------
// 256 WGs x 512 threads (8 waves, 2/SIMD -- R9 lesson: occupancy is load-
// bearing). grp = blockIdx%8 owns 32 batch rows; w = blockIdx/8 owns 32 hidden
// cols. Wave wv = (pv = wv&1 gate-pair, qv = wv>>1 K-quarter): one A-load
// feeds 2 MFMAs => A-LDS-reads halved vs R7. Cooperative whole-hs stage + WG
// barrier (NOT R8's LDS-atomic team spin). gbuf transposed [tile][col][row]
// (R9): b128 scatter, b64 elementwise reads, zero measured conflicts. XW in
// 12 regs/thread; tokens 2-bit packed. Exchange/sync protocol = R7-proven.
__global__ __launch_bounds__(512, 2)
void lstm_kernel(const int* __restrict__ x, const float* __restrict__ XW,
                 const unsigned short* __restrict__ Wt,
                 unsigned int* __restrict__ hbuf32, int* __restrict__ flags,
                 int* __restrict__ xflag) {
    __shared__ __align__(16) unsigned short hs[32 * 1032]; // h stage +8 pad  (66048 B)
    __shared__ __align__(16) float gbufT[16][32][36];      // [g*4+q][col][row] (73728 B)
    __shared__ unsigned char xtokp[4096];                  // [step][rowblock] 2-bit packed
    __shared__ int use_local_sh;

    const int tid  = threadIdx.x;
    const int grp  = blockIdx.x & 7;
    const int w    = blockIdx.x >> 3;
    const int wv   = tid >> 6;
    const int pv   = wv & 1;                   // gate-pair: gates 2pv, 2pv+1
    const int qv   = wv >> 1;                  // K-quarter
    const int lane = tid & 63;
    const int m32  = lane & 31;
    const int hv5  = lane >> 5;

    // ---- XCD-locality check (one-time, system-scope => placement-safe) ----
    {
        int xcc = 0;
        asm volatile("s_getreg_b32 %0, hwreg(HW_REG_XCC_ID)" : "=s"(xcc));
        if (tid == 0) {
            __hip_atomic_store(&xflag[grp * 32 + w], xcc + 1, __ATOMIC_RELAXED,
                               __HIP_MEMORY_SCOPE_SYSTEM);
        }
        if (wv == 0) {
            int v;
            for (;;) {
                v = __hip_atomic_load(&xflag[grp * 32 + (lane & 31)], __ATOMIC_RELAXED,
                                      __HIP_MEMORY_SCOPE_SYSTEM);
                if (__all(v != 0)) break;
                __builtin_amdgcn_s_sleep(2);
            }
            int v0 = __shfl(v, 0, 64);
            if (lane == 0) use_local_sh = __all(v == v0) ? 1 : 0;
        }
    }

    // one-time: B fragments for both gates of the pair (128 regs/lane)
    bf16x8 Bf0[16], Bf1[16];
    {
        const unsigned short* wb0 = Wt + (size_t)(((w * 4 + 2 * pv + 0) * 4 + qv) * 16) * 512
                                       + (size_t)lane * 8;
        const unsigned short* wb1 = Wt + (size_t)(((w * 4 + 2 * pv + 1) * 4 + qv) * 16) * 512
                                       + (size_t)lane * 8;
        #pragma unroll
        for (int i = 0; i < 16; ++i) {
            Bf0[i] = *(const bf16x8*)(wb0 + i * 512);
            Bf1[i] = *(const bf16x8*)(wb1 + i * 512);
        }
    }

    // elementwise ownership: col c = tid&31 (== m32), rows rb, rb+1
    // rb = 4*wv' ... precisely rb = 2*(tid>>5) = 4*wv + 2*hv5
    const int c  = m32;
    const int rb = 2 * (tid >> 5);

    // one-time: XW for this thread's column, all toks/gates -> 12 registers
    float xw0[4], xw1[4], xw2[4];
    #pragma unroll
    for (int g = 0; g < 4; ++g) {
        xw0[g] = XW[(0 * 4 + g) * HID + w * 32 + c];
        xw1[g] = XW[(1 * 4 + g) * HID + w * 32 + c];
        xw2[g] = XW[(2 * 4 + g) * HID + w * 32 + c];
    }

    // one-time: token table, byte = 4 rowblock tokens at one step
    for (int i = tid; i < 4096; i += 512) {
        int s_ = i >> 3, blk = i & 7;
        int t0 = x[(grp * 32 + blk * 4 + 0) * T_SEQ + s_] & 3;
        int t1 = x[(grp * 32 + blk * 4 + 1) * T_SEQ + s_] & 3;
        int t2 = x[(grp * 32 + blk * 4 + 2) * T_SEQ + s_] & 3;
        int t3 = x[(grp * 32 + blk * 4 + 3) * T_SEQ + s_] & 3;
        xtokp[i] = (unsigned char)(t0 | (t1 << 2) | (t2 << 4) | (t3 << 6));
    }
    __syncthreads();
    const bool use_local = (use_local_sh != 0);

    float cst[2] = {0.f, 0.f};
    unsigned long long* hs64 = (unsigned long long*)hs;

    for (int s = 0; s < T_SEQ; ++s) {
        // ---- wait for h(s) from all 32 group members (flags start at 0) ----
        if (s > 0) {
            if (wv == 0) {
                const int fidx = grp * 32 + (lane & 31);
                if (use_local) {
                    while (__hip_atomic_load(&flags[fidx], __ATOMIC_RELAXED,
                                             __HIP_MEMORY_SCOPE_AGENT) < s)
                        __builtin_amdgcn_s_sleep(1);
                } else {
                    while (__hip_atomic_load(&flags[fidx], __ATOMIC_RELAXED,
                                             __HIP_MEMORY_SCOPE_SYSTEM) < s)
                        __builtin_amdgcn_s_sleep(1);
                }
            }
            __syncthreads();
        }

        // ---- cooperative stage: h(s)[32 rows x 1024] into padded LDS ----
        const unsigned long long* hp64 = (const unsigned long long*)
            (hbuf32 + (size_t)(s & 1) * (BATCH * HID / 2));
        {
            unsigned long long tmp[16];
            #pragma unroll
            for (int it = 0; it < 16; ++it) {
                int flat = it * 512 + tid;             // 8192 qwords
                const unsigned long long* src =
                    &hp64[(size_t)(grp * 32 + (flat >> 8)) * 256 + (flat & 255)];
                tmp[it] = use_local
                    ? __hip_atomic_load(src, __ATOMIC_RELAXED, __HIP_MEMORY_SCOPE_AGENT)
                    : __hip_atomic_load(src, __ATOMIC_RELAXED, __HIP_MEMORY_SCOPE_SYSTEM);
            }
            #pragma unroll
            for (int it = 0; it < 16; ++it) {
                int flat = it * 512 + tid;
                hs64[(flat >> 8) * 258 + (flat & 255)] = tmp[it];
            }
        }
        __syncthreads();

        // ---- GEMM: 2 gates x 32x32 over this wave's K-quarter ----
        floatx16 acc0 = (floatx16)(0.f);
        floatx16 acc1 = (floatx16)(0.f);
        const unsigned short* ap = hs + m32 * 1032 + qv * 256 + hv5 * 8;
        #pragma unroll
        for (int i = 0; i < 16; ++i) {
            bf16x8 a = *(const bf16x8*)(ap + i * 16);
            acc0 = __builtin_amdgcn_mfma_f32_32x32x16_bf16(a, Bf0[i], acc0, 0, 0, 0);
            acc1 = __builtin_amdgcn_mfma_f32_32x32x16_bf16(a, Bf1[i], acc1, 0, 0, 0);
        }

        // ---- transposed scatter: regs 4rr..4rr+3 = rows 8rr+4hv5.. (b128) ----
        #pragma unroll
        for (int rr = 0; rr < 4; ++rr) {
            floatx4 v0 = { acc0[4 * rr + 0], acc0[4 * rr + 1],
                           acc0[4 * rr + 2], acc0[4 * rr + 3] };
            floatx4 v1 = { acc1[4 * rr + 0], acc1[4 * rr + 1],
                           acc1[4 * rr + 2], acc1[4 * rr + 3] };
            *(floatx4*)&gbufT[(2 * pv + 0) * 4 + qv][m32][8 * rr + 4 * hv5] = v0;
            *(floatx4*)&gbufT[(2 * pv + 1) * 4 + qv][m32][8 * rr + 4 * hv5] = v1;
        }
        __syncthreads();   // B1: all 16 partial tiles ready

        // ---- elementwise: col c, rows rb, rb+1 ----
        {
            int byte = xtokp[s * 8 + (rb >> 2)];
            floatx2 ag = *(const floatx2*)&gbufT[0][c][rb]  + *(const floatx2*)&gbufT[1][c][rb]
                       + *(const floatx2*)&gbufT[2][c][rb]  + *(const floatx2*)&gbufT[3][c][rb];
            floatx2 ai = *(const floatx2*)&gbufT[4][c][rb]  + *(const floatx2*)&gbufT[5][c][rb]
                       + *(const floatx2*)&gbufT[6][c][rb]  + *(const floatx2*)&gbufT[7][c][rb];
            floatx2 af = *(const floatx2*)&gbufT[8][c][rb]  + *(const floatx2*)&gbufT[9][c][rb]
                       + *(const floatx2*)&gbufT[10][c][rb] + *(const floatx2*)&gbufT[11][c][rb];
            floatx2 ao = *(const floatx2*)&gbufT[12][c][rb] + *(const floatx2*)&gbufT[13][c][rb]
                       + *(const floatx2*)&gbufT[14][c][rb] + *(const floatx2*)&gbufT[15][c][rb];
            unsigned short* hnext = (unsigned short*)
                (hbuf32 + (size_t)((s + 1) & 1) * (BATCH * HID / 2));
            #pragma unroll
            for (int i = 0; i < 2; ++i) {
                int tk = (byte >> (2 * ((rb & 3) + i))) & 3;
                float xg = tk == 0 ? xw0[0] : (tk == 1 ? xw1[0] : xw2[0]);
                float xi = tk == 0 ? xw0[1] : (tk == 1 ? xw1[1] : xw2[1]);
                float xf = tk == 0 ? xw0[2] : (tk == 1 ? xw1[2] : xw2[2]);
                float xo = tk == 0 ? xw0[3] : (tk == 1 ? xw1[3] : xw2[3]);
                float g  = tanh_fast(ag[i] + xg);
                float ii = sig_fast(ai[i] + xi);
                float ff = sig_fast(af[i] + xf);
                float oo = sig_fast(ao[i] + xo);
                float cn = g * ii + cst[i] * ff;
                float h  = tanh_fast(cn) * oo;
                cst[i]   = (tk != 0) ? cn : 0.0f;   // pad = ((x+1)//2) in {0,1,1}
                unsigned short hv = (unsigned short)f2bf(h);
                unsigned short* hp = &hnext[(size_t)(grp * 32 + rb + i) * HID + w * 32 + c];
                if (use_local) {
                    __hip_atomic_store(hp, hv, __ATOMIC_RELAXED, __HIP_MEMORY_SCOPE_WORKGROUP);
                } else {
                    __hip_atomic_store(hp, hv, __ATOMIC_RELAXED, __HIP_MEMORY_SCOPE_SYSTEM);
                }
            }
        }
        // syncthreads drains each wave's vmcnt before s_barrier => on exit, all
        // h stores of this WG are complete at their coherence point.
        __syncthreads();

        if (s < T_SEQ - 1 && tid == 0) {
            if (use_local) {
                __hip_atomic_store(&flags[grp * 32 + w], s + 1,
                                   __ATOMIC_RELAXED, __HIP_MEMORY_SCOPE_WORKGROUP);
            } else {
                __hip_atomic_store(&flags[grp * 32 + w], s + 1,
                                   __ATOMIC_RELAXED, __HIP_MEMORY_SCOPE_SYSTEM);
            }
        }
    }
}

// -------------------- projection + log_softmax over batch dim ---------------
__global__ void proj_kernel(const unsigned short* __restrict__ h,
                            const float* __restrict__ wph, const float* __restrict__ bp,
                            float* __restrict__ out) {
    __shared__ float wl[HID * NCLS];
    __shared__ float red[256];
    int tid = threadIdx.x;      // = batch row
    for (int i = tid; i < HID * NCLS; i += 256) wl[i] = wph[i];
    __syncthreads();
    float p[NCLS];
    #pragma unroll
    for (int c2 = 0; c2 < NCLS; ++c2) p[c2] = bp[c2];
    const unsigned short* hr = h + tid * HID;
    for (int k0 = 0; k0 < HID / 8; ++k0) {
        bf16x8 hv = *(const bf16x8*)(hr + k0 * 8);
        #pragma unroll
        for (int j = 0; j < 8; ++j) {
            float hk = (float)hv[j];
            #pragma unroll
            for (int c2 = 0; c2 < NCLS; ++c2) p[c2] += hk * wl[(k0 * 8 + j) * NCLS + c2];
        }
    }
    for (int c2 = 0; c2 < NCLS; ++c2) {
        red[tid] = p[c2];
        __syncthreads();
        for (int s = 128; s > 0; s >>= 1) {
            if (tid < s) red[tid] = fmaxf(red[tid], red[tid + s]);
            __syncthreads();
        }
        float mx = red[0];
        __syncthreads();
        red[tid] = __expf(p[c2] - mx);
        __syncthreads();
        for (int s = 128; s > 0; s >>= 1) {
            if (tid < s) red[tid] += red[tid + s];
            __syncthreads();
        }
        float lse = mx + __logf(red[0]);
        __syncthreads();
        out[tid * NCLS + c2] = p[c2] - lse;
    }
}

// ----------------------------------------------------------------------------
extern "C" void kernel_launch(void* const* d_in, const int* in_sizes, int n_in,
                              void* d_out, int out_size, void* d_ws, size_t ws_size,
                              hipStream_t stream) {
    const int*   x    = (const int*)d_in[0];
    const float* emb  = (const float*)d_in[1];
    const float* wgx  = (const float*)d_in[2];
    const float* wgh  = (const float*)d_in[3];
    const float* bg_  = (const float*)d_in[4];
    const float* wix  = (const float*)d_in[5];
    const float* wih  = (const float*)d_in[6];
    const float* bi_  = (const float*)d_in[7];
    const float* wfx  = (const float*)d_in[8];
    const float* wfh  = (const float*)d_in[9];
    const float* bf_  = (const float*)d_in[10];
    const float* wox  = (const float*)d_in[11];
    const float* woh  = (const float*)d_in[12];
    const float* bo_  = (const float*)d_in[13];
    const float* wph  = (const float*)d_in[14];
    const float* bp_  = (const float*)d_in[15];
    float* out = (float*)d_out;

    char* wsp = (char*)d_ws;
    int*            flags = (int*)wsp;                                      // 4 KB
    int*            xflag = (int*)(wsp + 4096);                             // 4 KB
    float*          XW    = (float*)(wsp + 8192);                           // 48 KB
    unsigned short* Wt    = (unsigned short*)(wsp + 8192 + 49152);          // 8 MB
    unsigned int*   hbuf32= (unsigned int*)(wsp + 8192 + 49152 + 8388608);  // 1 MB

    hipMemsetAsync(flags, 0, 8192, stream);                                  // flags+xflag
    hipMemsetAsync(hbuf32, 0, BATCH * HID * sizeof(unsigned short), stream); // h0 = 0

    prep_xw_kernel<<<48, 256, 0, stream>>>(emb, wgx, wix, wfx, wox,
                                           bg_, bi_, bf_, bo_, XW);
    prep_w_kernel<<<8192, 64, 0, stream>>>(wgh, wih, wfh, woh, Wt);

    void* args[] = { (void*)&x, (void*)&XW, (void*)&Wt, (void*)&hbuf32,
                     (void*)&flags, (void*)&xflag };
    hipError_t cerr = hipLaunchCooperativeKernel((void*)lstm_kernel, dim3(256), dim3(512),
                                                 args, 0, stream);
    if (cerr != hipSuccess) {
        // Fallback: plain launch. The flag protocol needs only co-residency,
        // which grid=256 at 1 WG/CU provides.
        lstm_kernel<<<dim3(256), dim3(512), 0, stream>>>(x, XW, Wt, hbuf32, flags, xflag);
    }

    proj_kernel<<<1, 256, 0, stream>>>((const unsigned short*)hbuf32, wph, bp_, out);
}

// Round 11
// 1926.084 us; speedup vs baseline: 2.2029x; 1.0426x over previous
//
#include <hip/hip_runtime.h>
#include <hip/hip_bf16.h>

#define T_SEQ 512
#define BATCH 256
#define HID   1024
#define EMBD  256
#define NCLS  10

typedef __bf16 bf16x8 __attribute__((ext_vector_type(8)));
typedef float  floatx16 __attribute__((ext_vector_type(16)));
typedef float  floatx2 __attribute__((ext_vector_type(2)));
typedef unsigned short ushortx8 __attribute__((ext_vector_type(8)));

__device__ __forceinline__ unsigned int f2bf(float f) {
    unsigned int u = __builtin_bit_cast(unsigned int, f);
    u += 0x7fffu + ((u >> 16) & 1u);
    return u >> 16;
}
__device__ __forceinline__ float sig_fast(float x) {
    return __builtin_amdgcn_rcpf(1.0f + __expf(-x));
}
__device__ __forceinline__ float tanh_fast(float x) {
    return 1.0f - 2.0f * __builtin_amdgcn_rcpf(1.0f + __expf(2.0f * x));
}

// -------------------- prep: XW[tok][gate][n] = emb[tok] @ Wx_gate + b_gate ---
__global__ void prep_xw_kernel(const float* __restrict__ emb,
                               const float* __restrict__ wgx, const float* __restrict__ wix,
                               const float* __restrict__ wfx, const float* __restrict__ wox,
                               const float* __restrict__ bg,  const float* __restrict__ bi,
                               const float* __restrict__ bf,  const float* __restrict__ bo,
                               float* __restrict__ XW) {
    int gid = blockIdx.x * blockDim.x + threadIdx.x;     // 3*4*1024 = 12288
    if (gid >= 3 * 4 * HID) return;
    int tok  = gid >> 12;
    int gate = (gid >> 10) & 3;
    int n    = gid & 1023;
    const float* W = gate == 0 ? wgx : gate == 1 ? wix : gate == 2 ? wfx : wox;
    const float* B = gate == 0 ? bg  : gate == 1 ? bi  : gate == 2 ? bf  : bo;
    float acc = B[n];
    const float* e = emb + tok * EMBD;
    for (int k = 0; k < EMBD; ++k) acc += e[k] * W[k * HID + n];
    XW[gid] = acc;
}

// ---- prep: Wt in 32x32x16 MFMA B-fragment order, K-quarter granularity ----
// frag = ((w*4+g)*4+q)*16 + i ; Wt[frag*512 + lane*8 + e]
//   = bf16( W_g[k = q*256 + i*16 + (lane>>5)*8 + e][j = w*32 + (lane&31)] )
__global__ void prep_w_kernel(const float* __restrict__ wgh, const float* __restrict__ wih,
                              const float* __restrict__ wfh, const float* __restrict__ woh,
                              unsigned short* __restrict__ Wt) {
    int bid = blockIdx.x;                 // 8192 = g(2b) q(2b) i(4b) w(5b)
    int w   = bid & 31;
    int i   = (bid >> 5) & 15;
    int q   = (bid >> 9) & 3;
    int g   = bid >> 11;
    const float* W = g == 0 ? wgh : g == 1 ? wih : g == 2 ? wfh : woh;
    int lane = threadIdx.x;               // 64
    int j    = w * 32 + (lane & 31);
    int k0   = q * 256 + i * 16 + (lane >> 5) * 8;
    ushortx8 o8;
    #pragma unroll
    for (int e = 0; e < 8; ++e) o8[e] = (unsigned short)f2bf(W[(k0 + e) * HID + j]);
    int frag = ((w * 4 + g) * 4 + q) * 16 + i;
    *(ushortx8*)&Wt[frag * 512 + lane * 8] = o8;
}

// -------------------- persistent recurrent kernel ---------------------------
// R7 structure verbatim (champion: 1760us) with ONE delta: wave = (gate-pair
// pv, K-quarter qv) so each A-load feeds two MFMAs -> A-LDS-reads halved
// (R10's good half). gbuf stays ROW-MAJOR [tile][row][col+pad] with R7's
// scalar b32 scatter and R7's exact elementwise (xwl in LDS, b64 reads in the
// verified 0-conflict phase pattern, b32 packed h-stores) -- avoiding R10's
// poisons (b64 transposed reads = 2-way in-phase conflicts; register-XW
// v_cndmask chains; subword stores). Stage/spin/publish/scopes = R7-proven.
__global__ __launch_bounds__(512, 2)
void lstm_kernel(const int* __restrict__ x, const float* __restrict__ XW,
                 const unsigned short* __restrict__ Wt,
                 unsigned int* __restrict__ hbuf32, int* __restrict__ flags,
                 int* __restrict__ xflag) {
    __shared__ __align__(16) unsigned short hs[32 * 1032]; // h stage +8 pad (66048 B)
    __shared__ float gbuf[16][32][36];         // [g*4+q][row][col+pad]     (73728 B)
    __shared__ float xwl[384];                 // [tok][gate][32 cols]      (1536 B)
    __shared__ unsigned char xtok[32 * 512];   // tokens, byte-packed       (16384 B)
    __shared__ int use_local_sh;

    const int tid  = threadIdx.x;
    const int grp  = blockIdx.x & 7;
    const int w    = blockIdx.x >> 3;
    const int wv   = tid >> 6;
    const int pv   = wv & 1;                   // gate-pair: gates 2pv, 2pv+1
    const int qv   = wv >> 1;                  // K-quarter
    const int lane = tid & 63;
    const int m32  = lane & 31;
    const int hv5  = lane >> 5;

    // ---- XCD-locality check (one-time, system-scope => placement-safe) ----
    {
        int xcc = 0;
        asm volatile("s_getreg_b32 %0, hwreg(HW_REG_XCC_ID)" : "=s"(xcc));
        if (tid == 0) {
            __hip_atomic_store(&xflag[grp * 32 + w], xcc + 1, __ATOMIC_RELAXED,
                               __HIP_MEMORY_SCOPE_SYSTEM);
        }
        if (wv == 0) {
            int v;
            for (;;) {
                v = __hip_atomic_load(&xflag[grp * 32 + (lane & 31)], __ATOMIC_RELAXED,
                                      __HIP_MEMORY_SCOPE_SYSTEM);
                if (__all(v != 0)) break;
                __builtin_amdgcn_s_sleep(2);
            }
            int v0 = __shfl(v, 0, 64);
            if (lane == 0) use_local_sh = __all(v == v0) ? 1 : 0;
        }
    }

    // one-time: B fragments for both gates of the pair (128 regs/lane)
    bf16x8 Bf0[16], Bf1[16];
    {
        const unsigned short* wb0 = Wt + (size_t)(((w * 4 + 2 * pv + 0) * 4 + qv) * 16) * 512
                                       + (size_t)lane * 8;
        const unsigned short* wb1 = Wt + (size_t)(((w * 4 + 2 * pv + 1) * 4 + qv) * 16) * 512
                                       + (size_t)lane * 8;
        #pragma unroll
        for (int i = 0; i < 16; ++i) {
            Bf0[i] = *(const bf16x8*)(wb0 + i * 512);
            Bf1[i] = *(const bf16x8*)(wb1 + i * 512);
        }
    }
    // one-time: XW slice into LDS
    if (tid < 384) {
        int tok = tid >> 7, g = (tid >> 5) & 3, jl = tid & 31;
        xwl[tid] = XW[(tok * 4 + g) * HID + w * 32 + jl];
    }
    // one-time: token table into LDS (byte-packed, R7 layout)
    #pragma unroll
    for (int it = 0; it < 32; ++it) {
        int flat = it * 512 + tid;                 // 16384 tokens
        int row  = flat >> 9;
        int col  = flat & 511;
        xtok[flat] = (unsigned char)x[(grp * 32 + row) * T_SEQ + col];
    }
    __syncthreads();
    const bool use_local = (use_local_sh != 0);

    // elementwise ownership (R7): thread -> row = tid>>4, cols jc2*2..+2
    const int erow = tid >> 4;
    const int jc2  = tid & 15;
    float cst[2] = {0.f, 0.f};
    unsigned long long* hs64 = (unsigned long long*)hs;

    for (int s = 0; s < T_SEQ; ++s) {
        // ---- wait for h(s) from all 32 group members (flags start at 0) ----
        if (s > 0) {
            if (wv == 0) {
                const int fidx = grp * 32 + (lane & 31);
                if (use_local) {
                    while (__hip_atomic_load(&flags[fidx], __ATOMIC_RELAXED,
                                             __HIP_MEMORY_SCOPE_AGENT) < s)
                        __builtin_amdgcn_s_sleep(1);
                } else {
                    while (__hip_atomic_load(&flags[fidx], __ATOMIC_RELAXED,
                                             __HIP_MEMORY_SCOPE_SYSTEM) < s)
                        __builtin_amdgcn_s_sleep(1);
                }
            }
            __syncthreads();
        }

        // ---- cooperative stage: h(s)[32 rows x 1024] into padded LDS ----
        {
            const unsigned long long* hp64 = (const unsigned long long*)
                (hbuf32 + (size_t)(s & 1) * (BATCH * HID / 2));
            unsigned long long tmp[16];
            #pragma unroll
            for (int it = 0; it < 16; ++it) {
                int flat = it * 512 + tid;             // 8192 qwords
                const unsigned long long* src =
                    &hp64[(size_t)(grp * 32 + (flat >> 8)) * 256 + (flat & 255)];
                tmp[it] = use_local
                    ? __hip_atomic_load(src, __ATOMIC_RELAXED, __HIP_MEMORY_SCOPE_AGENT)
                    : __hip_atomic_load(src, __ATOMIC_RELAXED, __HIP_MEMORY_SCOPE_SYSTEM);
            }
            #pragma unroll
            for (int it = 0; it < 16; ++it) {
                int flat = it * 512 + tid;
                hs64[(flat >> 8) * 258 + (flat & 255)] = tmp[it];
            }
        }
        __syncthreads();

        // ---- GEMM: 2 gates x 32x32 over this wave's K-quarter ----
        floatx16 acc0 = (floatx16)(0.f);
        floatx16 acc1 = (floatx16)(0.f);
        const unsigned short* ap = hs + m32 * 1032 + qv * 256 + hv5 * 8;
        #pragma unroll
        for (int i = 0; i < 16; ++i) {
            bf16x8 a = *(const bf16x8*)(ap + i * 16);
            acc0 = __builtin_amdgcn_mfma_f32_32x32x16_bf16(a, Bf0[i], acc0, 0, 0, 0);
            acc1 = __builtin_amdgcn_mfma_f32_32x32x16_bf16(a, Bf1[i], acc1, 0, 0, 0);
        }

        // ---- scatter C (col=lane&31, row=(reg&3)+8*(reg>>2)+4*(lane>>5)) ----
        {
            float* gb0 = &gbuf[(2 * pv + 0) * 4 + qv][0][0];
            float* gb1 = &gbuf[(2 * pv + 1) * 4 + qv][0][0];
            #pragma unroll
            for (int reg = 0; reg < 16; ++reg) {
                int row = (reg & 3) + 8 * (reg >> 2) + 4 * hv5;
                gb0[row * 36 + m32] = acc0[reg];
                gb1[row * 36 + m32] = acc1[reg];
            }
        }
        __syncthreads();   // B1: all 16 partial tiles ready

        // ---- elementwise (R7 exact shape): row erow, cols jc2*2..+2 ----
        {
            int tk = xtok[erow * 512 + s];
            const float* xb = &xwl[tk * 128];
            const int go = erow * 36 + jc2 * 2;
            #define SUMQ(g) (*(const floatx2*)&gbuf[(g)*4+0][0][go] \
                           + *(const floatx2*)&gbuf[(g)*4+1][0][go] \
                           + *(const floatx2*)&gbuf[(g)*4+2][0][go] \
                           + *(const floatx2*)&gbuf[(g)*4+3][0][go])
            floatx2 ag = SUMQ(0);
            floatx2 ai = SUMQ(1);
            floatx2 af = SUMQ(2);
            floatx2 ao = SUMQ(3);
            #undef SUMQ
            floatx2 xg = *(const floatx2*)&xb[0 * 32 + jc2 * 2];
            floatx2 xi = *(const floatx2*)&xb[1 * 32 + jc2 * 2];
            floatx2 xf = *(const floatx2*)&xb[2 * 32 + jc2 * 2];
            floatx2 xo = *(const floatx2*)&xb[3 * 32 + jc2 * 2];
            unsigned int hvv[2];
            #pragma unroll
            for (int u = 0; u < 2; ++u) {
                float g  = tanh_fast(ag[u] + xg[u]);
                float ii = sig_fast(ai[u] + xi[u]);
                float ff = sig_fast(af[u] + xf[u]);
                float oo = sig_fast(ao[u] + xo[u]);
                float cn = g * ii + cst[u] * ff;
                float h  = tanh_fast(cn) * oo;
                cst[u]   = (tk != 0) ? cn : 0.0f;   // pad = ((x+1)//2) in {0,1,1}
                hvv[u]   = f2bf(h);
            }
            unsigned int* hnext = hbuf32 + (size_t)((s + 1) & 1) * (BATCH * HID / 2);
            unsigned int* hp = &hnext[((grp * 32 + erow) * HID + w * 32 + jc2 * 2) >> 1];
            unsigned int hval = hvv[0] | (hvv[1] << 16);
            if (use_local) {
                __hip_atomic_store(hp, hval, __ATOMIC_RELAXED, __HIP_MEMORY_SCOPE_WORKGROUP);
            } else {
                __hip_atomic_store(hp, hval, __ATOMIC_RELAXED, __HIP_MEMORY_SCOPE_SYSTEM);
            }
        }
        // syncthreads drains each wave's vmcnt before s_barrier => on exit, all
        // h stores of this WG are complete at their coherence point.
        __syncthreads();

        if (s < T_SEQ - 1 && tid == 0) {
            if (use_local) {
                __hip_atomic_store(&flags[grp * 32 + w], s + 1,
                                   __ATOMIC_RELAXED, __HIP_MEMORY_SCOPE_WORKGROUP);
            } else {
                __hip_atomic_store(&flags[grp * 32 + w], s + 1,
                                   __ATOMIC_RELAXED, __HIP_MEMORY_SCOPE_SYSTEM);
            }
        }
    }
}

// -------------------- projection + log_softmax over batch dim ---------------
__global__ void proj_kernel(const unsigned short* __restrict__ h,
                            const float* __restrict__ wph, const float* __restrict__ bp,
                            float* __restrict__ out) {
    __shared__ float wl[HID * NCLS];
    __shared__ float red[256];
    int tid = threadIdx.x;      // = batch row
    for (int i = tid; i < HID * NCLS; i += 256) wl[i] = wph[i];
    __syncthreads();
    float p[NCLS];
    #pragma unroll
    for (int c2 = 0; c2 < NCLS; ++c2) p[c2] = bp[c2];
    const unsigned short* hr = h + tid * HID;
    for (int k0 = 0; k0 < HID / 8; ++k0) {
        bf16x8 hv = *(const bf16x8*)(hr + k0 * 8);
        #pragma unroll
        for (int j = 0; j < 8; ++j) {
            float hk = (float)hv[j];
            #pragma unroll
            for (int c2 = 0; c2 < NCLS; ++c2) p[c2] += hk * wl[(k0 * 8 + j) * NCLS + c2];
        }
    }
    for (int c2 = 0; c2 < NCLS; ++c2) {
        red[tid] = p[c2];
        __syncthreads();
        for (int s = 128; s > 0; s >>= 1) {
            if (tid < s) red[tid] = fmaxf(red[tid], red[tid + s]);
            __syncthreads();
        }
        float mx = red[0];
        __syncthreads();
        red[tid] = __expf(p[c2] - mx);
        __syncthreads();
        for (int s = 128; s > 0; s >>= 1) {
            if (tid < s) red[tid] += red[tid + s];
            __syncthreads();
        }
        float lse = mx + __logf(red[0]);
        __syncthreads();
        out[tid * NCLS + c2] = p[c2] - lse;
    }
}

// ----------------------------------------------------------------------------
extern "C" void kernel_launch(void* const* d_in, const int* in_sizes, int n_in,
                              void* d_out, int out_size, void* d_ws, size_t ws_size,
                              hipStream_t stream) {
    const int*   x    = (const int*)d_in[0];
    const float* emb  = (const float*)d_in[1];
    const float* wgx  = (const float*)d_in[2];
    const float* wgh  = (const float*)d_in[3];
    const float* bg_  = (const float*)d_in[4];
    const float* wix  = (const float*)d_in[5];
    const float* wih  = (const float*)d_in[6];
    const float* bi_  = (const float*)d_in[7];
    const float* wfx  = (const float*)d_in[8];
    const float* wfh  = (const float*)d_in[9];
    const float* bf_  = (const float*)d_in[10];
    const float* wox  = (const float*)d_in[11];
    const float* woh  = (const float*)d_in[12];
    const float* bo_  = (const float*)d_in[13];
    const float* wph  = (const float*)d_in[14];
    const float* bp_  = (const float*)d_in[15];
    float* out = (float*)d_out;

    char* wsp = (char*)d_ws;
    int*            flags = (int*)wsp;                                      // 4 KB
    int*            xflag = (int*)(wsp + 4096);                             // 4 KB
    float*          XW    = (float*)(wsp + 8192);                           // 48 KB
    unsigned short* Wt    = (unsigned short*)(wsp + 8192 + 49152);          // 8 MB
    unsigned int*   hbuf32= (unsigned int*)(wsp + 8192 + 49152 + 8388608);  // 1 MB

    hipMemsetAsync(flags, 0, 8192, stream);                                  // flags+xflag
    hipMemsetAsync(hbuf32, 0, BATCH * HID * sizeof(unsigned short), stream); // h0 = 0

    prep_xw_kernel<<<48, 256, 0, stream>>>(emb, wgx, wix, wfx, wox,
                                           bg_, bi_, bf_, bo_, XW);
    prep_w_kernel<<<8192, 64, 0, stream>>>(wgh, wih, wfh, woh, Wt);

    void* args[] = { (void*)&x, (void*)&XW, (void*)&Wt, (void*)&hbuf32,
                     (void*)&flags, (void*)&xflag };
    hipError_t cerr = hipLaunchCooperativeKernel((void*)lstm_kernel, dim3(256), dim3(512),
                                                 args, 0, stream);
    if (cerr != hipSuccess) {
        // Fallback: plain launch. The flag protocol needs only co-residency,
        // which grid=256 at 1 WG/CU provides.
        lstm_kernel<<<dim3(256), dim3(512), 0, stream>>>(x, XW, Wt, hbuf32, flags, xflag);
    }

    proj_kernel<<<1, 256, 0, stream>>>((const unsigned short*)hbuf32, wph, bp_, out);
}